// Round 4
// baseline (281.904 us; speedup 1.0000x reference)
//
#include <hip/hip_runtime.h>

// Fused attention with masked-key compaction, 5 dispatches, dense tile enumeration
// with XCD-aware grouping. R12 changes vs R11:
//  (1) qkvt grid 1024 -> 1536. T = 512 + 16*MTp; with p=0.5 mask, rowsK ~ 33-36
//      -> MTp=40 -> T=1152 > 1024: 128 blocks ran TWO tiles serially while the
//      rest idled (qkvt 59us ~= 2x single-tile 30us, MfmaUtil 25%). 1536 covers
//      the worst case (all-unmasked -> T=1536); dead blocks exit in ~100 cycles.
//  (2) gather_x dispatch removed: K-GEMM A-panel and Vt-GEMM B-panel read xh
//      through sel[] directly (global_load_lds src is per-lane; row pointers
//      hoisted outside the K-loop). Rows >= counts clamp to sel[cnt-1] (dup of
//      last key, finite): softmax masks idx>=counts and P[k]=0 for k>=counts,
//      so dup K/V columns never reach the output (same guarantee zero-pad gave).
// R8 lesson retained: __launch_bounds__ second arg MUST be 4 (5 forced VGPR
// 64->48 and spilled acc: WRITE 34->301MB, MfmaUtil 26->9%).
// R9/R10 lesson: deep-pipeline 8-phase regressed here (1 block/CU exposes every
// stall; K=1024 can't amortize prologues). Occupancy > pipeline depth.
//  L1 prep:    cast x,W -> f16; per-batch mask scan (sel/counts/npad)
//  L3 qkvt:    {Q(512), K(8*MTp), Vt(8*MTp)} XCD-grouped, G=1536 @4/CU
//  L4 s128:    S = (Q Kc^T)/32, 128x128 body, Kc-panel-grouped, G=1024
//  L5 softmax: wave-per-row
//  L6 pv128:   O = P @ Vt^T (K=npad), 128x128 body, Sbuf-panel-grouped, G=512
// GEMM core: BK=64, global_load_lds w=16, XOR-swizzled LDS (0 conflicts, R2).
// NOTE (R7): ~70 us of wall is harness re-poison fills inside the timed window.

typedef _Float16 f16;
typedef _Float16 f16x4 __attribute__((ext_vector_type(4)));
typedef _Float16 f16x8 __attribute__((ext_vector_type(8)));
typedef float f32x4 __attribute__((ext_vector_type(4)));

#define LB256 __launch_bounds__(256)

__device__ __forceinline__ void gld16(const void* gp, void* lp) {
  __builtin_amdgcn_global_load_lds(
      (__attribute__((address_space(1))) void*)(gp),
      (__attribute__((address_space(3))) void*)(lp),
      16, 0, 0);
}

// ---------------------------------------------------------------- 128x128 GEMM body
// Optional row indirection: selA/selB map tile-local row -> source row of A/B
// (clamped to cnt-1). Row pointers are hoisted out of the K-loop.
template <typename OutT>
__device__ __forceinline__ void gemm_body(
    f16* As, f16* Bs,
    const f16* __restrict__ A, int lda, const f16* __restrict__ B, int ldb,
    OutT* __restrict__ C, int ldc,
    const float* __restrict__ bias1, const float* __restrict__ bias2, int nb1,
    int bias_row, float scale, int K, int m0, int n0,
    const int* __restrict__ selA, int cntA,
    const int* __restrict__ selB, int cntB) {
  const int tid = threadIdx.x;
  const int w = tid >> 6, l = tid & 63;
  const int wm = (w >> 1) * 64, wn = (w & 1) * 64;
  const int quad = l >> 4, lo = l & 15;
  const int rl = l >> 3;
  const int scol = ((l & 7) ^ rl) * 8;
  const int swz = (quad ^ (lo & 3)) * 8;
  const int ks0 = ((lo >> 2) & 1) * 32;

  const f16* arow[4];
  const f16* brow[4];
#pragma unroll
  for (int r = 0; r < 4; ++r) {
    const int row = (r * 4 + w) * 8 + rl;
    int ra = m0 + row;
    if (selA) ra = selA[ra < cntA ? ra : cntA - 1];
    arow[r] = A + (long)ra * lda + scol;
    int rb = n0 + row;
    if (selB) rb = selB[rb < cntB ? rb : cntB - 1];
    brow[r] = B + (long)rb * ldb + scol;
  }

  f32x4 acc[4][4] = {};
  for (int kk = 0; kk < K; kk += 64) {
#pragma unroll
    for (int r = 0; r < 4; ++r) {
      const int c8 = r * 4 + w;
      gld16(arow[r] + kk, &As[c8 * 512]);
      gld16(brow[r] + kk, &Bs[c8 * 512]);
    }
    __syncthreads();
#pragma unroll
    for (int ks = 0; ks < 2; ++ks) {
      const int kso = ks ? (32 - ks0) : ks0;
      f16x8 af[4], bf[4];
#pragma unroll
      for (int i = 0; i < 4; ++i)
        af[i] = *(const f16x8*)&As[(wm + i * 16 + lo) * 64 + swz + kso];
#pragma unroll
      for (int j = 0; j < 4; ++j)
        bf[j] = *(const f16x8*)&Bs[(wn + j * 16 + lo) * 64 + swz + kso];
#pragma unroll
      for (int i = 0; i < 4; ++i)
#pragma unroll
        for (int j = 0; j < 4; ++j)
          acc[i][j] = __builtin_amdgcn_mfma_f32_16x16x32_f16(af[i], bf[j],
                                                             acc[i][j], 0, 0, 0);
    }
    __syncthreads();
  }
#pragma unroll
  for (int i = 0; i < 4; ++i) {
    const int rowb = m0 + wm + i * 16 + quad * 4;
#pragma unroll
    for (int j = 0; j < 4; ++j) {
      const int col = n0 + wn + j * 16 + lo;
      float bc = 0.f;
      if (bias1 && !bias_row) bc = (col < nb1) ? bias1[col] : bias2[col - nb1];
#pragma unroll
      for (int r = 0; r < 4; ++r) {
        float bv = bias_row ? bias1[rowb + r] : bc;
        C[(long)(rowb + r) * ldc + col] = (OutT)(acc[i][j][r] * scale + bv);
      }
    }
  }
}

// ---------------------------------------------------------------- L1 prep
__global__ LB256 void prep(const float* __restrict__ x, const float* __restrict__ wq,
                           const float* __restrict__ wk, const float* __restrict__ wv,
                           const void* __restrict__ maskp, f16* __restrict__ xh,
                           f16* __restrict__ wh, int* __restrict__ sel,
                           int* __restrict__ counts, int* __restrict__ npad) {
  const int blk = blockIdx.x;
  const int t = threadIdx.x;
  if (blk < 11264) {
    long i = ((long)blk * 256 + t) * 4;
    const float* src;
    f16* dst;
    if (i < 8388608L) {
      src = x + i;
      dst = xh + i;
    } else {
      long j = i - 8388608L;
      int which = (int)(j >> 20);
      const float* ws = which == 0 ? wq : (which == 1 ? wk : wv);
      src = ws + (j & 1048575L);
      dst = wh + j;
    }
    float4 v = *(const float4*)src;
    f16x4 o;
    o[0] = (f16)v.x; o[1] = (f16)v.y; o[2] = (f16)v.z; o[3] = (f16)v.w;
    *(f16x4*)dst = o;
  } else {
    const int b = blk - 11264;
    __shared__ int bad;
    __shared__ int s[256];
    if (t == 0) bad = 0;
    __syncthreads();
    const int* mi = (const int*)maskp;
    int loc = 0;
    for (int i = t; i < 2048; i += 256)
      if ((unsigned)mi[i] > 1u) loc = 1;  // byte-packed bools look like big ints
    if (loc) atomicOr(&bad, 1);
    __syncthreads();
    const bool bytemode = bad != 0;
    int m[8];
    if (bytemode) {
      const unsigned char* p = (const unsigned char*)maskp + b * 2048 + t * 8;
#pragma unroll
      for (int e = 0; e < 8; ++e) m[e] = p[e] != 0;
    } else {
      const int* p = mi + b * 2048 + t * 8;
#pragma unroll
      for (int e = 0; e < 8; ++e) m[e] = p[e] != 0;
    }
    int local = 0;
#pragma unroll
    for (int e = 0; e < 8; ++e) local += m[e];
    s[t] = local;
    __syncthreads();
    for (int off = 1; off < 256; off <<= 1) {
      int v = (t >= off) ? s[t - off] : 0;
      __syncthreads();
      s[t] += v;
      __syncthreads();
    }
    int offp = s[t] - local;
#pragma unroll
    for (int e = 0; e < 8; ++e)
      if (m[e]) sel[b * 2048 + offp++] = t * 8 + e;
    if (t == 0) {
      counts[b] = s[255];
      npad[b] = ((s[255] + 127) >> 7) << 7;
    }
  }
}

// ---------------------------------------------------------------- L3 Q+K+Vt (XCD-grouped)
// Q tiles [0,512): id = n*64 + m -> the 8 n-tiles sharing A-rows m have ids = m
// (mod 8) -> same XCD L2. K/Vt: per-batch row-tiles flattened to r in [0,rowsK),
// padded to MTp (mult of 8); K id = 512 + n*MTp + r; Vt id = base2 + m*MTp + r.
// K/Vt gather xh rows via sel[] in the staging loads (no xc buffer).
__global__ __launch_bounds__(256, 4) void qkvt_gemm(
    const f16* __restrict__ xh, const f16* __restrict__ Wh, f16* __restrict__ Qb,
    f16* __restrict__ Kc, f16* __restrict__ Vt, const float* __restrict__ bq,
    const float* __restrict__ bk, const float* __restrict__ bv,
    const int* __restrict__ sel, const int* __restrict__ counts,
    const int* __restrict__ npad) {
  __shared__ __align__(16) f16 As[128 * 64];
  __shared__ __align__(16) f16 Bs[128 * 64];
  int cum[5];
  cum[0] = 0;
#pragma unroll
  for (int b = 0; b < 4; ++b) cum[b + 1] = cum[b] + (npad[b] >> 7);
  const int rowsK = cum[4];
  const int MTp = (rowsK + 7) & ~7;
  const int base2 = 512 + 8 * MTp;
  const int T = base2 + 8 * MTp;

  for (int tile = blockIdx.x; tile < T; tile += gridDim.x) {
    if (tile < 512) {
      const int m = tile & 63, n = tile >> 6;
      gemm_body<f16>(As, Bs, xh, 1024, Wh, 1024, Qb, 1024, bq, bq, 1 << 30, 0,
                     1.0f, 1024, m * 128, n * 128, nullptr, 0, nullptr, 0);
    } else if (tile < base2) {
      const int u = tile - 512;
      const int n = u / MTp, r = u % MTp;
      if (r >= rowsK) continue;
      int b = 0;
      while (r >= cum[b + 1]) ++b;
      const int m = r - cum[b];
      gemm_body<f16>(As, Bs, xh + (long)b * 2097152, 1024, Wh + 1048576, 1024,
                     Kc + (long)b * 2097152, 1024, bk, bk, 1 << 30, 0, 1.0f,
                     1024, m * 128, n * 128, sel + b * 2048, counts[b],
                     nullptr, 0);
    } else {
      const int u = tile - base2;
      const int m = u / MTp, r = u % MTp;
      if (r >= rowsK) continue;
      int b = 0;
      while (r >= cum[b + 1]) ++b;
      const int n = r - cum[b];
      gemm_body<f16>(As, Bs, Wh + 2097152, 1024, xh + (long)b * 2097152, 1024,
                     Vt + (long)b * 2097152, 2048, bv, bv, 0, 1, 1.0f, 1024,
                     m * 128, n * 128, nullptr, 0, sel + b * 2048, counts[b]);
    }
  }
}

// ---------------------------------------------------------------- L4 S GEMM (128x128)
// Group by shared Kc panel (each Kc n-tile is read by 16 m-tiles): flatten (b,n)
// to rn in [0,rowsN), pad to Np (mult of 8); id = m*Np + rn -> same rn same XCD.
__global__ __launch_bounds__(256, 4) void s_gemm128(
    const f16* __restrict__ Qb, const f16* __restrict__ Kc, f16* __restrict__ Sbuf,
    const int* __restrict__ npad) {
  __shared__ __align__(16) f16 As[128 * 64];
  __shared__ __align__(16) f16 Bs[128 * 64];
  int cum[5];
  cum[0] = 0;
#pragma unroll
  for (int b = 0; b < 4; ++b) cum[b + 1] = cum[b] + (npad[b] >> 7);
  const int rowsN = cum[4];
  const int Np = (rowsN + 7) & ~7;
  const int T = 16 * Np;

  for (int tile = blockIdx.x; tile < T; tile += gridDim.x) {
    const int m = tile / Np, rn = tile % Np;
    if (rn >= rowsN) continue;
    int b = 0;
    while (rn >= cum[b + 1]) ++b;
    const int n = rn - cum[b];
    gemm_body<f16>(As, Bs, Qb + (long)b * 2097152, 1024,
                   Kc + (long)b * 2097152, 1024,
                   Sbuf + (long)b * 4194304, 2048, nullptr, nullptr, 0, 0,
                   0.03125f, 1024, m * 128, n * 128, nullptr, 0, nullptr, 0);
  }
}

// ---------------------------------------------------------------- L5 softmax (wave-per-row)
__global__ LB256 void softmax_w(f16* __restrict__ S, const int* __restrict__ counts,
                                const int* __restrict__ npad) {
  const int wv = threadIdx.x >> 6, l = threadIdx.x & 63;
  const long r = (long)blockIdx.x * 4 + wv;
  const int b = (int)(r >> 11);
  const int nv = counts[b], np = npad[b];
  f16* row = S + r * 2048;

  float v[4][8];
  bool have[4];
  float mx = -3.0e38f;
#pragma unroll
  for (int g = 0; g < 4; ++g) {
    const int idx = (g * 64 + l) * 8;
    have[g] = idx < np;
    if (have[g]) {
      f16x8 sv = *(const f16x8*)(row + idx);
#pragma unroll
      for (int e = 0; e < 8; ++e) {
        float s = (idx + e < nv) ? (float)sv[e] : -3.0e38f;
        v[g][e] = s;
        mx = fmaxf(mx, s);
      }
    } else {
#pragma unroll
      for (int e = 0; e < 8; ++e) v[g][e] = -3.0e38f;
    }
  }
#pragma unroll
  for (int off = 32; off > 0; off >>= 1) mx = fmaxf(mx, __shfl_xor(mx, off, 64));

  float sum = 0.f;
  float ev[4][8];
#pragma unroll
  for (int g = 0; g < 4; ++g)
#pragma unroll
    for (int e = 0; e < 8; ++e) {
      float t = (v[g][e] <= -1.0e38f) ? 0.f : __expf(v[g][e] - mx);
      ev[g][e] = t;
      sum += t;
    }
#pragma unroll
  for (int off = 32; off > 0; off >>= 1) sum += __shfl_xor(sum, off, 64);
  const float inv = 1.f / sum;
#pragma unroll
  for (int g = 0; g < 4; ++g) {
    if (!have[g]) continue;
    const int idx = (g * 64 + l) * 8;
    f16x8 ov;
#pragma unroll
    for (int e = 0; e < 8; ++e) ov[e] = (f16)(ev[g][e] * inv);
    *(f16x8*)(row + idx) = ov;
  }
}

// ---------------------------------------------------------------- L6 PV GEMM (128x128)
// O = P @ Vt^T (K=npad). rm = b*16+m in [0,64); id = n*64 + rm: the 8 n-tiles
// sharing Sbuf rows (b,m) have ids = rm (mod 8) -> same XCD. T = 512 exact.
__global__ __launch_bounds__(256, 4) void pv_gemm128(
    const f16* __restrict__ Sbuf, const f16* __restrict__ Vt,
    float* __restrict__ out, const int* __restrict__ npad) {
  __shared__ __align__(16) f16 As[128 * 64];
  __shared__ __align__(16) f16 Bs[128 * 64];
  const int tile = blockIdx.x;
  const int n = tile >> 6, rm = tile & 63, b = rm >> 4, m = rm & 15;
  gemm_body<float>(As, Bs, Sbuf + (long)b * 4194304, 2048,
                   Vt + (long)b * 2097152, 2048, out + (long)b * 2097152,
                   1024, nullptr, nullptr, 0, 0, 1.0f, npad[b], m * 128,
                   n * 128, nullptr, 0, nullptr, 0);
}

// ---------------------------------------------------------------- launch
extern "C" void kernel_launch(void* const* d_in, const int* in_sizes, int n_in,
                              void* d_out, int out_size, void* d_ws, size_t ws_size,
                              hipStream_t stream) {
  const float* x = (const float*)d_in[0];
  const void* mask = d_in[1];
  const float* Wq = (const float*)d_in[2];
  const float* bq = (const float*)d_in[3];
  const float* Wk = (const float*)d_in[4];
  const float* bk = (const float*)d_in[5];
  const float* Wv = (const float*)d_in[6];
  const float* bv = (const float*)d_in[7];
  float* out = (float*)d_out;

  // Workspace (f16 elems), 118 MB total (proven available in R1).
  // xc slot retained in the map but no longer written (gather fused into qkvt).
  f16* xh = (f16*)d_ws;              // 8M  [0,16MB)
  f16* xc = xh + 8388608;            // 8M  [16,32)  (unused)
  f16* Wh = xc + 8388608;            // 3M  [32,38)  [Wq|Wk|Wv]
  f16* Qb = Wh + 3145728;            // 8M  [38,54)
  f16* Kc = Qb + 8388608;            // 8M  [54,70)
  f16* Vt = Kc + 8388608;            // 8M  [70,86)
  f16* Sbuf = Vt + 8388608;          // 16M [86,118)
  int* sel = (int*)(Sbuf + 16777216);
  int* counts = sel + 8192;
  int* npad = counts + 4;

  prep<<<11268, 256, 0, stream>>>(x, Wq, Wk, Wv, mask, xh, Wh, sel, counts, npad);
  qkvt_gemm<<<1536, 256, 0, stream>>>(xh, Wh, Qb, Kc, Vt, bq, bk, bv, sel,
                                      counts, npad);
  s_gemm128<<<1024, 256, 0, stream>>>(Qb, Kc, Sbuf, npad);
  softmax_w<<<2048, 256, 0, stream>>>(Sbuf, counts, npad);
  pv_gemm128<<<512, 256, 0, stream>>>(Sbuf, Vt, out, npad);
}

// Round 5
// 229.606 us; speedup vs baseline: 1.2278x; 1.2278x over previous
//
#include <hip/hip_runtime.h>

// Fused attention with masked-key compaction, 6 dispatches, dense tile enumeration
// with XCD-aware grouping. R13 = R11 + qkvt tail-packing. R12 post-mortem:
// sel-gather fusion spilled (WRITE 34->100MB, FETCH 42->87MB, MfmaUtil 14%) --
// the 64-VGPR body has ZERO register headroom; gather_x restored. Grid-size
// bump alone cannot fix the qkvt tail (1024 resident slots, T~1152 equal tiles
// -> ~128-tile straggler round at 12% util). Fix: K and Vt use the 64x128 body
// (cost 1/2, same 32KB LDS union -> still 4/CU): T ~= 512x1 + 576x0.5 + 640x0.5
// ~= 1088 cost-units on 1024 slots -> tail packs.
// R8 lesson: __launch_bounds__ 2nd arg MUST be 4 on the 128-body (5 spills).
// R9/R10 lesson: deep-pipeline 8-phase regressed (occupancy > pipeline depth).
//  L1 prep:    cast x,W -> f16; per-batch mask scan (sel/counts/npad)
//  L2 gather:  xc[b][s'] = xh[b][sel[s']] (pad rows zeroed)
//  L3 qkvt:    Q(512 @128x128) + K(8n x npad/64 @64x128) + Vt(16m x npad/128
//              @64x128), XCD-grouped ids, G=1792 grid-stride
//  L4 s128:    S = (Q Kc^T)/32, 128x128 body, Kc-panel-grouped, G=1024
//  L5 softmax: wave-per-row
//  L6 pv128:   O = P @ Vt^T (K=npad), 128x128 body, Sbuf-panel-grouped, G=512
// GEMM cores: BK=64, global_load_lds w=16, XOR-swizzled LDS (0 conflicts, R2).
// NOTE (R7): ~70 us of wall is harness re-poison fills inside the timed window.

typedef _Float16 f16;
typedef _Float16 f16x4 __attribute__((ext_vector_type(4)));
typedef _Float16 f16x8 __attribute__((ext_vector_type(8)));
typedef float f32x4 __attribute__((ext_vector_type(4)));

#define LB256 __launch_bounds__(256)

__device__ __forceinline__ void gld16(const void* gp, void* lp) {
  __builtin_amdgcn_global_load_lds(
      (__attribute__((address_space(1))) void*)(gp),
      (__attribute__((address_space(3))) void*)(lp),
      16, 0, 0);
}

// ---------------------------------------------------------------- 128x128 GEMM body
template <typename OutT>
__device__ __forceinline__ void gemm_body(
    f16* As, f16* Bs,
    const f16* __restrict__ A, int lda, const f16* __restrict__ B, int ldb,
    OutT* __restrict__ C, int ldc,
    const float* __restrict__ bias1, const float* __restrict__ bias2, int nb1,
    int bias_row, float scale, int K, int m0, int n0) {
  const int tid = threadIdx.x;
  const int w = tid >> 6, l = tid & 63;
  const int wm = (w >> 1) * 64, wn = (w & 1) * 64;
  const int quad = l >> 4, lo = l & 15;
  const int rl = l >> 3;
  const int scol = ((l & 7) ^ rl) * 8;
  const int swz = (quad ^ (lo & 3)) * 8;
  const int ks0 = ((lo >> 2) & 1) * 32;

  f32x4 acc[4][4] = {};
  for (int kk = 0; kk < K; kk += 64) {
#pragma unroll
    for (int r = 0; r < 4; ++r) {
      const int c8 = r * 4 + w;
      const int row = c8 * 8 + rl;
      gld16(A + (long)(m0 + row) * lda + kk + scol, &As[c8 * 512]);
      gld16(B + (long)(n0 + row) * ldb + kk + scol, &Bs[c8 * 512]);
    }
    __syncthreads();
#pragma unroll
    for (int ks = 0; ks < 2; ++ks) {
      const int kso = ks ? (32 - ks0) : ks0;
      f16x8 af[4], bf[4];
#pragma unroll
      for (int i = 0; i < 4; ++i)
        af[i] = *(const f16x8*)&As[(wm + i * 16 + lo) * 64 + swz + kso];
#pragma unroll
      for (int j = 0; j < 4; ++j)
        bf[j] = *(const f16x8*)&Bs[(wn + j * 16 + lo) * 64 + swz + kso];
#pragma unroll
      for (int i = 0; i < 4; ++i)
#pragma unroll
        for (int j = 0; j < 4; ++j)
          acc[i][j] = __builtin_amdgcn_mfma_f32_16x16x32_f16(af[i], bf[j],
                                                             acc[i][j], 0, 0, 0);
    }
    __syncthreads();
  }
#pragma unroll
  for (int i = 0; i < 4; ++i) {
    const int rowb = m0 + wm + i * 16 + quad * 4;
#pragma unroll
    for (int j = 0; j < 4; ++j) {
      const int col = n0 + wn + j * 16 + lo;
      float bc = 0.f;
      if (bias1 && !bias_row) bc = (col < nb1) ? bias1[col] : bias2[col - nb1];
#pragma unroll
      for (int r = 0; r < 4; ++r) {
        float bv = bias_row ? bias1[rowb + r] : bc;
        C[(long)(rowb + r) * ldc + col] = (OutT)(acc[i][j][r] * scale + bv);
      }
    }
  }
}

// ---------------------------------------------------------------- 64x128 GEMM body
// R8-proven body + bias: bias_row=0 -> +bias[col] (if bias), =1 -> +bias[row].
template <typename OutT>
__device__ __forceinline__ void gemm_body64(
    f16* As, f16* Bs,
    const f16* __restrict__ A, int lda, const f16* __restrict__ B, int ldb,
    OutT* __restrict__ C, int ldc, const float* __restrict__ bias, int bias_row,
    float scale, int K, int m0, int n0) {
  const int tid = threadIdx.x;
  const int w = tid >> 6, l = tid & 63;
  const int wm = (w >> 1) * 32, wn = (w & 1) * 64;
  const int quad = l >> 4, lo = l & 15;
  const int rl = l >> 3;
  const int scol = ((l & 7) ^ rl) * 8;
  const int swz = (quad ^ (lo & 3)) * 8;
  const int ks0 = ((lo >> 2) & 1) * 32;

  f32x4 acc[2][4] = {};
  for (int kk = 0; kk < K; kk += 64) {
#pragma unroll
    for (int r = 0; r < 2; ++r) {
      const int c8 = w * 2 + r;
      gld16(A + (long)(m0 + c8 * 8 + rl) * lda + kk + scol, &As[c8 * 512]);
    }
#pragma unroll
    for (int r = 0; r < 4; ++r) {
      const int c8 = w * 4 + r;
      gld16(B + (long)(n0 + c8 * 8 + rl) * ldb + kk + scol, &Bs[c8 * 512]);
    }
    __syncthreads();
#pragma unroll
    for (int ks = 0; ks < 2; ++ks) {
      const int kso = ks ? (32 - ks0) : ks0;
      f16x8 af[2], bf[4];
#pragma unroll
      for (int i = 0; i < 2; ++i)
        af[i] = *(const f16x8*)&As[(wm + i * 16 + lo) * 64 + swz + kso];
#pragma unroll
      for (int j = 0; j < 4; ++j)
        bf[j] = *(const f16x8*)&Bs[(wn + j * 16 + lo) * 64 + swz + kso];
#pragma unroll
      for (int i = 0; i < 2; ++i)
#pragma unroll
        for (int j = 0; j < 4; ++j)
          acc[i][j] = __builtin_amdgcn_mfma_f32_16x16x32_f16(af[i], bf[j],
                                                             acc[i][j], 0, 0, 0);
    }
    __syncthreads();
  }
#pragma unroll
  for (int i = 0; i < 2; ++i) {
    const int rowb = m0 + wm + i * 16 + quad * 4;
#pragma unroll
    for (int j = 0; j < 4; ++j) {
      const int col = n0 + wn + j * 16 + lo;
      const float bc = (bias && !bias_row) ? bias[col] : 0.f;
#pragma unroll
      for (int r = 0; r < 4; ++r) {
        const float bv = (bias && bias_row) ? bias[rowb + r] : bc;
        C[(long)(rowb + r) * ldc + col] = (OutT)(acc[i][j][r] * scale + bv);
      }
    }
  }
}

// ---------------------------------------------------------------- L1 prep
__global__ LB256 void prep(const float* __restrict__ x, const float* __restrict__ wq,
                           const float* __restrict__ wk, const float* __restrict__ wv,
                           const void* __restrict__ maskp, f16* __restrict__ xh,
                           f16* __restrict__ wh, int* __restrict__ sel,
                           int* __restrict__ counts, int* __restrict__ npad) {
  const int blk = blockIdx.x;
  const int t = threadIdx.x;
  if (blk < 11264) {
    long i = ((long)blk * 256 + t) * 4;
    const float* src;
    f16* dst;
    if (i < 8388608L) {
      src = x + i;
      dst = xh + i;
    } else {
      long j = i - 8388608L;
      int which = (int)(j >> 20);
      const float* ws = which == 0 ? wq : (which == 1 ? wk : wv);
      src = ws + (j & 1048575L);
      dst = wh + j;
    }
    float4 v = *(const float4*)src;
    f16x4 o;
    o[0] = (f16)v.x; o[1] = (f16)v.y; o[2] = (f16)v.z; o[3] = (f16)v.w;
    *(f16x4*)dst = o;
  } else {
    const int b = blk - 11264;
    __shared__ int bad;
    __shared__ int s[256];
    if (t == 0) bad = 0;
    __syncthreads();
    const int* mi = (const int*)maskp;
    int loc = 0;
    for (int i = t; i < 2048; i += 256)
      if ((unsigned)mi[i] > 1u) loc = 1;  // byte-packed bools look like big ints
    if (loc) atomicOr(&bad, 1);
    __syncthreads();
    const bool bytemode = bad != 0;
    int m[8];
    if (bytemode) {
      const unsigned char* p = (const unsigned char*)maskp + b * 2048 + t * 8;
#pragma unroll
      for (int e = 0; e < 8; ++e) m[e] = p[e] != 0;
    } else {
      const int* p = mi + b * 2048 + t * 8;
#pragma unroll
      for (int e = 0; e < 8; ++e) m[e] = p[e] != 0;
    }
    int local = 0;
#pragma unroll
    for (int e = 0; e < 8; ++e) local += m[e];
    s[t] = local;
    __syncthreads();
    for (int off = 1; off < 256; off <<= 1) {
      int v = (t >= off) ? s[t - off] : 0;
      __syncthreads();
      s[t] += v;
      __syncthreads();
    }
    int offp = s[t] - local;
#pragma unroll
    for (int e = 0; e < 8; ++e)
      if (m[e]) sel[b * 2048 + offp++] = t * 8 + e;
    if (t == 0) {
      counts[b] = s[255];
      npad[b] = ((s[255] + 127) >> 7) << 7;
    }
  }
}

// ---------------------------------------------------------------- L2 gather
__global__ LB256 void gather_x(const f16* __restrict__ xh, const int* __restrict__ sel,
                               const int* __restrict__ counts,
                               const int* __restrict__ npad, f16* __restrict__ xc) {
  const int b = blockIdx.y;
  const int np = npad[b], cnt = counts[b];
  const int t = threadIdx.x;
#pragma unroll
  for (int i = 0; i < 4; ++i) {
    const int sp = blockIdx.x * 4 + i;
    if (sp >= np) continue;
    f16* dst = xc + ((long)b * 2048 + sp) * 1024;
    if (sp >= cnt) {
      *(f16x4*)(dst + t * 4) = (f16x4){0, 0, 0, 0};
    } else {
      const f16* src = xh + ((long)b * 2048 + sel[b * 2048 + sp]) * 1024;
      *(f16x4*)(dst + t * 4) = *(const f16x4*)(src + t * 4);
    }
  }
}

// ---------------------------------------------------------------- L3 Q+K+Vt (XCD-grouped, mixed tile sizes)
// Q [0,512): 128x128 body, id = n*64 + m (same-m ids == m mod 8 -> same XCD).
// K: 64x128 body over r64 in [0,rows64) = flatten(b, npad/64 m-tiles), padded
//    to M64p (mult 8); id = 512 + n*M64p + r64, n in [0,8).
// Vt: 64x128 body, m16 in [0,16) x rv in [0,rowsV) = flatten(b, npad/128
//    col-tiles), padded MVp; id = baseV + m16*MVp + rv.
__global__ __launch_bounds__(256, 4) void qkvt_gemm(
    const f16* __restrict__ xh, const f16* __restrict__ xc,
    const f16* __restrict__ Wh, f16* __restrict__ Qb, f16* __restrict__ Kc,
    f16* __restrict__ Vt, const float* __restrict__ bq,
    const float* __restrict__ bk, const float* __restrict__ bv,
    const int* __restrict__ npad) {
  __shared__ __align__(16) f16 As[128 * 64];
  __shared__ __align__(16) f16 Bs[128 * 64];
  int c64[5], cv[5];
  c64[0] = cv[0] = 0;
#pragma unroll
  for (int b = 0; b < 4; ++b) {
    c64[b + 1] = c64[b] + (npad[b] >> 6);
    cv[b + 1] = cv[b] + (npad[b] >> 7);
  }
  const int rows64 = c64[4], rowsV = cv[4];
  const int M64p = (rows64 + 7) & ~7;
  const int MVp = (rowsV + 7) & ~7;
  const int baseV = 512 + 8 * M64p;
  const int T = baseV + 16 * MVp;

  for (int tile = blockIdx.x; tile < T; tile += gridDim.x) {
    if (tile < 512) {
      const int m = tile & 63, n = tile >> 6;
      gemm_body<f16>(As, Bs, xh, 1024, Wh, 1024, Qb, 1024, bq, bq, 1 << 30, 0,
                     1.0f, 1024, m * 128, n * 128);
    } else if (tile < baseV) {
      const int u = tile - 512;
      const int n = u / M64p, r = u % M64p;
      if (r >= rows64) continue;
      int b = 0;
      while (r >= c64[b + 1]) ++b;
      const int m = r - c64[b];
      gemm_body64<f16>(As, Bs, xc + (long)b * 2097152, 1024, Wh + 1048576, 1024,
                       Kc + (long)b * 2097152, 1024, bk, 0, 1.0f, 1024, m * 64,
                       n * 128);
    } else {
      const int u = tile - baseV;
      const int m = u / MVp, r = u % MVp;
      if (r >= rowsV) continue;
      int b = 0;
      while (r >= cv[b + 1]) ++b;
      const int n = r - cv[b];
      gemm_body64<f16>(As, Bs, Wh + 2097152, 1024, xc + (long)b * 2097152, 1024,
                       Vt + (long)b * 2097152, 2048, bv, 1, 1.0f, 1024, m * 64,
                       n * 128);
    }
  }
}

// ---------------------------------------------------------------- L4 S GEMM (128x128)
// Group by shared Kc panel (each Kc n-tile is read by 16 m-tiles): flatten (b,n)
// to rn in [0,rowsN), pad to Np (mult of 8); id = m*Np + rn -> same rn same XCD.
__global__ __launch_bounds__(256, 4) void s_gemm128(
    const f16* __restrict__ Qb, const f16* __restrict__ Kc, f16* __restrict__ Sbuf,
    const int* __restrict__ npad) {
  __shared__ __align__(16) f16 As[128 * 64];
  __shared__ __align__(16) f16 Bs[128 * 64];
  int cum[5];
  cum[0] = 0;
#pragma unroll
  for (int b = 0; b < 4; ++b) cum[b + 1] = cum[b] + (npad[b] >> 7);
  const int rowsN = cum[4];
  const int Np = (rowsN + 7) & ~7;
  const int T = 16 * Np;

  for (int tile = blockIdx.x; tile < T; tile += gridDim.x) {
    const int m = tile / Np, rn = tile % Np;
    if (rn >= rowsN) continue;
    int b = 0;
    while (rn >= cum[b + 1]) ++b;
    const int n = rn - cum[b];
    gemm_body<f16>(As, Bs, Qb + (long)b * 2097152, 1024,
                   Kc + (long)b * 2097152, 1024,
                   Sbuf + (long)b * 4194304, 2048, nullptr, nullptr, 0, 0,
                   0.03125f, 1024, m * 128, n * 128);
  }
}

// ---------------------------------------------------------------- L5 softmax (wave-per-row)
__global__ LB256 void softmax_w(f16* __restrict__ S, const int* __restrict__ counts,
                                const int* __restrict__ npad) {
  const int wv = threadIdx.x >> 6, l = threadIdx.x & 63;
  const long r = (long)blockIdx.x * 4 + wv;
  const int b = (int)(r >> 11);
  const int nv = counts[b], np = npad[b];
  f16* row = S + r * 2048;

  float v[4][8];
  bool have[4];
  float mx = -3.0e38f;
#pragma unroll
  for (int g = 0; g < 4; ++g) {
    const int idx = (g * 64 + l) * 8;
    have[g] = idx < np;
    if (have[g]) {
      f16x8 sv = *(const f16x8*)(row + idx);
#pragma unroll
      for (int e = 0; e < 8; ++e) {
        float s = (idx + e < nv) ? (float)sv[e] : -3.0e38f;
        v[g][e] = s;
        mx = fmaxf(mx, s);
      }
    } else {
#pragma unroll
      for (int e = 0; e < 8; ++e) v[g][e] = -3.0e38f;
    }
  }
#pragma unroll
  for (int off = 32; off > 0; off >>= 1) mx = fmaxf(mx, __shfl_xor(mx, off, 64));

  float sum = 0.f;
  float ev[4][8];
#pragma unroll
  for (int g = 0; g < 4; ++g)
#pragma unroll
    for (int e = 0; e < 8; ++e) {
      float t = (v[g][e] <= -1.0e38f) ? 0.f : __expf(v[g][e] - mx);
      ev[g][e] = t;
      sum += t;
    }
#pragma unroll
  for (int off = 32; off > 0; off >>= 1) sum += __shfl_xor(sum, off, 64);
  const float inv = 1.f / sum;
#pragma unroll
  for (int g = 0; g < 4; ++g) {
    if (!have[g]) continue;
    const int idx = (g * 64 + l) * 8;
    f16x8 ov;
#pragma unroll
    for (int e = 0; e < 8; ++e) ov[e] = (f16)(ev[g][e] * inv);
    *(f16x8*)(row + idx) = ov;
  }
}

// ---------------------------------------------------------------- L6 PV GEMM (128x128)
// O = P @ Vt^T (K=npad). rm = b*16+m in [0,64); id = n*64 + rm: the 8 n-tiles
// sharing Sbuf rows (b,m) have ids = rm (mod 8) -> same XCD. T = 512 exact.
__global__ __launch_bounds__(256, 4) void pv_gemm128(
    const f16* __restrict__ Sbuf, const f16* __restrict__ Vt,
    float* __restrict__ out, const int* __restrict__ npad) {
  __shared__ __align__(16) f16 As[128 * 64];
  __shared__ __align__(16) f16 Bs[128 * 64];
  const int tile = blockIdx.x;
  const int n = tile >> 6, rm = tile & 63, b = rm >> 4, m = rm & 15;
  gemm_body<float>(As, Bs, Sbuf + (long)b * 4194304, 2048,
                   Vt + (long)b * 2097152, 2048, out + (long)b * 2097152,
                   1024, nullptr, nullptr, 0, 0, 1.0f, npad[b], m * 128,
                   n * 128);
}

// ---------------------------------------------------------------- launch
extern "C" void kernel_launch(void* const* d_in, const int* in_sizes, int n_in,
                              void* d_out, int out_size, void* d_ws, size_t ws_size,
                              hipStream_t stream) {
  const float* x = (const float*)d_in[0];
  const void* mask = d_in[1];
  const float* Wq = (const float*)d_in[2];
  const float* bq = (const float*)d_in[3];
  const float* Wk = (const float*)d_in[4];
  const float* bk = (const float*)d_in[5];
  const float* Wv = (const float*)d_in[6];
  const float* bv = (const float*)d_in[7];
  float* out = (float*)d_out;

  // Workspace (f16 elems), 118 MB total (proven available in R1).
  f16* xh = (f16*)d_ws;              // 8M  [0,16MB)
  f16* xc = xh + 8388608;            // 8M  [16,32)
  f16* Wh = xc + 8388608;            // 3M  [32,38)  [Wq|Wk|Wv]
  f16* Qb = Wh + 3145728;            // 8M  [38,54)
  f16* Kc = Qb + 8388608;            // 8M  [54,70)
  f16* Vt = Kc + 8388608;            // 8M  [70,86)
  f16* Sbuf = Vt + 8388608;          // 16M [86,118)
  int* sel = (int*)(Sbuf + 16777216);
  int* counts = sel + 8192;
  int* npad = counts + 4;

  prep<<<11268, 256, 0, stream>>>(x, Wq, Wk, Wv, mask, xh, Wh, sel, counts, npad);
  gather_x<<<dim3(512, 4), 256, 0, stream>>>(xh, sel, counts, npad, xc);
  qkvt_gemm<<<1792, 256, 0, stream>>>(xh, xc, Wh, Qb, Kc, Vt, bq, bk, bv, npad);
  s_gemm128<<<1024, 256, 0, stream>>>(Qb, Kc, Sbuf, npad);
  softmax_w<<<2048, 256, 0, stream>>>(Sbuf, counts, npad);
  pv_gemm128<<<512, 256, 0, stream>>>(Sbuf, Vt, out, npad);
}